// Round 3
// baseline (972.245 us; speedup 1.0000x reference)
//
#include <hip/hip_runtime.h>
#include <stdint.h>

#define T_DIM 8192
#define K_DIM 4096
#define N_DIM 4096

typedef __attribute__((ext_vector_type(8))) short bf16x8;
typedef __attribute__((ext_vector_type(8))) unsigned short u16x8;
typedef __attribute__((ext_vector_type(4))) float f32x4;

__device__ __forceinline__ unsigned short f2bf(float f) {
  union { float f; uint32_t u; } c; c.f = f;
  uint32_t u = c.u;
  uint32_t r = (u + 0x7fffu + ((u >> 16) & 1u)) >> 16;  // RNE
  return (unsigned short)r;
}
__device__ __forceinline__ float bf2f(unsigned short b) {
  union { uint32_t u; float f; } c; c.u = ((uint32_t)b) << 16;
  return c.f;
}

// ---------------- prep 1: unpack qweight -> Bt[n][k] = (w_int[k][n] - z[n]) as bf16 --------
// Bt stored TRANSPOSED (n-major): GEMM B-fragment load = 8 contiguous k. Writes coalesced
// (8 lanes cover one n's 128B row segment); reads are 8x32B clusters (qweight only 8MB, L3-ok).
__global__ void unpack_bt(const int* __restrict__ qweight, const int* __restrict__ qzeros,
                          unsigned short* __restrict__ bt) {
  const int t  = threadIdx.x;
  const int n  = blockIdx.y * 32 + (t >> 3);
  const int kk = blockIdx.x * 8 + (t & 7);          // packed-word index along K
  const int qw = qweight[(size_t)kk * N_DIM + n];
  const int zw = qzeros[n >> 3];
  const int z  = ((zw >> ((n & 7) * 4)) & 15) + 1;  // GPTQ +1
  u16x8 v;
#pragma unroll
  for (int i = 0; i < 8; ++i) {
    const int w = (qw >> (4 * i)) & 15;
    v[i] = f2bf((float)(w - z));                    // exact: integer in [-16,14]
  }
  *reinterpret_cast<u16x8*>(bt + (size_t)n * K_DIM + kk * 8) = v;
}

// ---------------- prep 2: split fp32 x into bf16 hi + lo, row-major [T][K] ----------------
__global__ void split_x(const float* __restrict__ x, unsigned short* __restrict__ xhi,
                        unsigned short* __restrict__ xlo, int n8) {
  const int stride = gridDim.x * blockDim.x;
  for (int i = blockIdx.x * blockDim.x + threadIdx.x; i < n8; i += stride) {
    const float4 v0 = reinterpret_cast<const float4*>(x)[2 * i + 0];
    const float4 v1 = reinterpret_cast<const float4*>(x)[2 * i + 1];
    const float f[8] = {v0.x, v0.y, v0.z, v0.w, v1.x, v1.y, v1.z, v1.w};
    u16x8 h, l;
#pragma unroll
    for (int j = 0; j < 8; ++j) {
      const unsigned short hb = f2bf(f[j]);
      h[j] = hb;
      l[j] = f2bf(f[j] - bf2f(hb));                 // exact residual in fp32, then RNE
    }
    reinterpret_cast<u16x8*>(xhi)[i] = h;
    reinterpret_cast<u16x8*>(xlo)[i] = l;
  }
}

// ---------------- GEMM: out = (xhi+xlo) @ Bt^T, epilogue scales/bias ----------------------
// 128x128 tile, BK=32, 4 waves (2x2), mfma_f32_16x16x32_bf16, dual-A (hi/lo) per B fragment.
// LDS FRAGMENT-MAJOR: frag f (16 rows x 32 k) = 1KB; lane l's 16B at f*1024 + l*16.
// Staged via global_load_lds(width=16) with per-lane pre-permuted global source address, so
// every ds_read_b128 is one fully linear 1KB wave access -> zero bank conflicts, no swizzle.
#define BM 128
#define BN 128
#define BK 32
#define NT (K_DIM / BK)
#define LDS_BUF 24576  /* Ahi 8K | Alo 8K | B 8K */

__device__ __forceinline__ void gll16(const unsigned short* g, void* l) {
  __builtin_amdgcn_global_load_lds(
      (const __attribute__((address_space(1))) unsigned int*)g,
      (__attribute__((address_space(3))) unsigned int*)l, 16, 0, 0);
}

__global__ __launch_bounds__(256, 3) void gemm_dual(
    const unsigned short* __restrict__ xhi, const unsigned short* __restrict__ xlo,
    const unsigned short* __restrict__ bt, const float* __restrict__ scales,
    const float* __restrict__ bias, float* __restrict__ out) {
  __shared__ char lds[2 * LDS_BUF];
  const int tid  = threadIdx.x;
  const int lane = tid & 63;
  const int wid  = tid >> 6;

  // T1: XCD-aware chunked swizzle (bijective: 2048 % 8 == 0, 256 blocks per XCD chunk).
  // Within a chunk blocks are N-fastest: 32 consecutive blocks share one 4MB A-panel in L2.
  const int bid = blockIdx.x;
  const int wg  = (bid & 7) * 256 + (bid >> 3);
  const int bx  = wg & 31;   // N tile (32)
  const int by  = wg >> 5;   // M tile (64)
  const int row0 = by * BM;
  const int col0 = bx * BN;

  const int r16 = lane & 15;
  const int kc  = lane >> 4;   // k-chunk 0..3 (8 contiguous bf16 each)
  const int fA  = wid * 2;     // this wave stages frags fA, fA+1 of each tensor

  const unsigned short* sA0 = xhi + (size_t)(row0 + (fA + 0) * 16 + r16) * K_DIM + kc * 8;
  const unsigned short* sA1 = xhi + (size_t)(row0 + (fA + 1) * 16 + r16) * K_DIM + kc * 8;
  const unsigned short* sL0 = xlo + (size_t)(row0 + (fA + 0) * 16 + r16) * K_DIM + kc * 8;
  const unsigned short* sL1 = xlo + (size_t)(row0 + (fA + 1) * 16 + r16) * K_DIM + kc * 8;
  const unsigned short* sB0 = bt  + (size_t)(col0 + (fA + 0) * 16 + r16) * K_DIM + kc * 8;
  const unsigned short* sB1 = bt  + (size_t)(col0 + (fA + 1) * 16 + r16) * K_DIM + kc * 8;

  f32x4 acc[4][4];
#pragma unroll
  for (int i = 0; i < 4; ++i)
#pragma unroll
    for (int j = 0; j < 4; ++j) acc[i][j] = (f32x4){0.f, 0.f, 0.f, 0.f};

  const int wr = wid >> 1;
  const int wc = wid & 1;

  auto stage = [&](int buf, int t) {
    char* base   = lds + buf * LDS_BUF;
    const int ko = t * BK;
    gll16(sA0 + ko, base +         (fA + 0) * 1024);
    gll16(sA1 + ko, base +         (fA + 1) * 1024);
    gll16(sL0 + ko, base +  8192 + (fA + 0) * 1024);
    gll16(sL1 + ko, base +  8192 + (fA + 1) * 1024);
    gll16(sB0 + ko, base + 16384 + (fA + 0) * 1024);
    gll16(sB1 + ko, base + 16384 + (fA + 1) * 1024);
  };

  stage(0, 0);
  asm volatile("s_waitcnt vmcnt(0)" ::: "memory");
  __builtin_amdgcn_s_barrier();

  int cur = 0;
  for (int t = 0; t < NT; ++t) {
    if (t + 1 < NT) stage(cur ^ 1, t + 1);  // issue next tile's loads early (T3 minimal)
    char* base = lds + cur * LDS_BUF;
    bf16x8 bf[4];
#pragma unroll
    for (int j = 0; j < 4; ++j)
      bf[j] = *reinterpret_cast<const bf16x8*>(base + 16384 + (wc * 4 + j) * 1024 + lane * 16);
#pragma unroll
    for (int i = 0; i < 4; ++i) {
      const bf16x8 ah = *reinterpret_cast<const bf16x8*>(base +        (wr * 4 + i) * 1024 + lane * 16);
      const bf16x8 al = *reinterpret_cast<const bf16x8*>(base + 8192 + (wr * 4 + i) * 1024 + lane * 16);
      // dependent (same-acc) MFMA pairs separated by 3 independent issues
#pragma unroll
      for (int j = 0; j < 4; ++j)
        acc[i][j] = __builtin_amdgcn_mfma_f32_16x16x32_bf16(ah, bf[j], acc[i][j], 0, 0, 0);
#pragma unroll
      for (int j = 0; j < 4; ++j)
        acc[i][j] = __builtin_amdgcn_mfma_f32_16x16x32_bf16(al, bf[j], acc[i][j], 0, 0, 0);
    }
    asm volatile("s_waitcnt vmcnt(0)" ::: "memory");
    __builtin_amdgcn_s_barrier();
    cur ^= 1;
  }

  // epilogue: out = scales[n]*acc + bias[n]; C/D layout (m89): col=lane&15, row=(lane>>4)*4+reg
#pragma unroll
  for (int j = 0; j < 4; ++j) {
    const int col = col0 + wc * 64 + j * 16 + r16;
    const float s = scales[col];
    const float b = bias[col];
#pragma unroll
    for (int i = 0; i < 4; ++i) {
      const int row = row0 + wr * 64 + i * 16 + kc * 4;
#pragma unroll
      for (int r = 0; r < 4; ++r) {
        out[(size_t)(row + r) * N_DIM + col] = s * acc[i][j][r] + b;
      }
    }
  }
}

extern "C" void kernel_launch(void* const* d_in, const int* in_sizes, int n_in,
                              void* d_out, int out_size, void* d_ws, size_t ws_size,
                              hipStream_t stream) {
  const float* x       = (const float*)d_in[0];
  const int*   qweight = (const int*)d_in[1];
  const int*   qzeros  = (const int*)d_in[2];
  const float* scales  = (const float*)d_in[3];
  // d_in[4] = g_idx: all zeros (single group) -> folded into Bt, unused
  const float* bias    = (const float*)d_in[5];
  float* out = (float*)d_out;

  char* ws = (char*)d_ws;
  unsigned short* bt  = (unsigned short*)ws;                               // 32 MB
  unsigned short* xhi = (unsigned short*)(ws + (size_t)32 * 1024 * 1024);  // 64 MB
  unsigned short* xlo = (unsigned short*)(ws + (size_t)96 * 1024 * 1024);  // 64 MB

  unpack_bt<<<dim3(K_DIM / 64, N_DIM / 32), 256, 0, stream>>>(qweight, qzeros, bt);
  split_x<<<dim3(4096), 256, 0, stream>>>(x, xhi, xlo, T_DIM * K_DIM / 8);
  gemm_dual<<<dim3((T_DIM / BM) * (N_DIM / BN)), 256, 0, stream>>>(xhi, xlo, bt, scales, bias, out);
}

// Round 4
// 875.695 us; speedup vs baseline: 1.1103x; 1.1103x over previous
//
#include <hip/hip_runtime.h>
#include <stdint.h>

#define T_DIM 8192
#define K_DIM 4096
#define N_DIM 4096

typedef __attribute__((ext_vector_type(8))) short bf16x8;
typedef __attribute__((ext_vector_type(8))) unsigned short u16x8;
typedef __attribute__((ext_vector_type(4))) float f32x4;

__device__ __forceinline__ unsigned short f2bf(float f) {
  union { float f; uint32_t u; } c; c.f = f;
  uint32_t u = c.u;
  uint32_t r = (u + 0x7fffu + ((u >> 16) & 1u)) >> 16;  // RNE
  return (unsigned short)r;
}
__device__ __forceinline__ float bf2f(unsigned short b) {
  union { uint32_t u; float f; } c; c.u = ((uint32_t)b) << 16;
  return c.f;
}

// ---------------- prep 1: unpack qweight -> Bt[n][k] = (w_int[k][n] - z[n]) as bf16 --------
__global__ void unpack_bt(const int* __restrict__ qweight, const int* __restrict__ qzeros,
                          unsigned short* __restrict__ bt) {
  const int t  = threadIdx.x;
  const int n  = blockIdx.y * 32 + (t >> 3);
  const int kk = blockIdx.x * 8 + (t & 7);          // packed-word index along K
  const int qw = qweight[(size_t)kk * N_DIM + n];
  const int zw = qzeros[n >> 3];
  const int z  = ((zw >> ((n & 7) * 4)) & 15) + 1;  // GPTQ +1
  u16x8 v;
#pragma unroll
  for (int i = 0; i < 8; ++i) {
    const int w = (qw >> (4 * i)) & 15;
    v[i] = f2bf((float)(w - z));                    // exact: integer in [-16,14]
  }
  *reinterpret_cast<u16x8*>(bt + (size_t)n * K_DIM + kk * 8) = v;
}

// ---------------- prep 2: split fp32 x into bf16 hi + lo, row-major [T][K] ----------------
__global__ void split_x(const float* __restrict__ x, unsigned short* __restrict__ xhi,
                        unsigned short* __restrict__ xlo, int n8) {
  const int stride = gridDim.x * blockDim.x;
  for (int i = blockIdx.x * blockDim.x + threadIdx.x; i < n8; i += stride) {
    const float4 v0 = reinterpret_cast<const float4*>(x)[2 * i + 0];
    const float4 v1 = reinterpret_cast<const float4*>(x)[2 * i + 1];
    const float f[8] = {v0.x, v0.y, v0.z, v0.w, v1.x, v1.y, v1.z, v1.w};
    u16x8 h, l;
#pragma unroll
    for (int j = 0; j < 8; ++j) {
      const unsigned short hb = f2bf(f[j]);
      h[j] = hb;
      l[j] = f2bf(f[j] - bf2f(hb));                 // exact residual in fp32, then RNE
    }
    reinterpret_cast<u16x8*>(xhi)[i] = h;
    reinterpret_cast<u16x8*>(xlo)[i] = l;
  }
}

// ---------------- GEMM: out = (xhi+xlo) @ Bt^T, 8-phase counted-vmcnt schedule ------------
// BM=128 BN=256 BK=64, 8 waves (2Mx4N), per-wave 64x64 out, dual-A (hi/lo) per B fragment.
// LDS FRAGMENT-MAJOR per 64KB buffer: Ahi 16K | Alo 16K | B 32K; frag = 16 rows x 32 k = 1KB,
// lane l's 16B at frag*1024 + l*16 (linear -> gll16-direct + conflict-free ds_read_b128,
// measured 0 bank conflicts in round 3). Per K-tile: 8 phases, prefetch of tile t+1 issued
// in phases 0-3 (2 gll16 each), ONE vmcnt(0) at phase 7 (T4: loads in flight across
// barriers, >=4 phases of MFMA cover), setprio around MFMA clusters (T5).
#define BM 128
#define BN 256
#define BK 64
#define NT (K_DIM / BK)   /* 64 */
#define BUF 65536         /* Ahi 16K | Alo 16K | B 32K */

__device__ __forceinline__ void gll16(const unsigned short* g, void* l) {
  __builtin_amdgcn_global_load_lds(
      (const __attribute__((address_space(1))) unsigned int*)g,
      (__attribute__((address_space(3))) unsigned int*)l, 16, 0, 0);
}

#define MFMA(a, b, c) __builtin_amdgcn_mfma_f32_16x16x32_bf16(a, b, c, 0, 0, 0)

__global__ __launch_bounds__(512, 2) void gemm_dual8(
    const unsigned short* __restrict__ xhi, const unsigned short* __restrict__ xlo,
    const unsigned short* __restrict__ bt, const float* __restrict__ scales,
    const float* __restrict__ bias, float* __restrict__ out) {
  __shared__ char lds[2 * BUF];
  const int tid  = threadIdx.x;
  const int lane = tid & 63;
  const int w    = tid >> 6;   // wave 0..7
  const int wr   = w >> 2;     // 0..1 (M)
  const int wc   = w & 3;      // 0..3 (N)
  const int r16  = lane & 15;
  const int kc   = lane >> 4;

  // T1: XCD swizzle, bijective (1024 % 8 == 0, 128 blocks per XCD chunk).
  const int bid = blockIdx.x;
  const int wg  = (bid & 7) * 128 + (bid >> 3);
  const int bx  = wg & 15;     // N tile (16) — fastest: 16 consecutive wg share the A-panel
  const int by  = wg >> 4;     // M tile (64)
  const int row0 = by * BM;
  const int col0 = bx * BN;

  // staging sources (wave w stages: Ahi rows [w*16,w*16+16) both k-halves, same Alo,
  // B cols [2w*16, (2w+2)*16) both k-halves). Frag-linear LDS dst, lane-linear source.
  const unsigned short* pA  = xhi + (size_t)(row0 + w * 16 + r16) * K_DIM + kc * 8;
  const unsigned short* pL  = xlo + (size_t)(row0 + w * 16 + r16) * K_DIM + kc * 8;
  const unsigned short* pB0 = bt  + (size_t)(col0 + (2 * w) * 16 + r16) * K_DIM + kc * 8;
  const unsigned short* pB2 = pB0 + (size_t)16 * K_DIM;

  f32x4 acc[4][4];
#pragma unroll
  for (int i = 0; i < 4; ++i)
#pragma unroll
    for (int j = 0; j < 4; ++j) acc[i][j] = (f32x4){0.f, 0.f, 0.f, 0.f};

  // prologue: stage tile 0 into buffer 0
  {
    char* b0 = lds;
    gll16(pA,       b0 + (2 * w + 0) * 1024);
    gll16(pA  + 32, b0 + (2 * w + 1) * 1024);
    gll16(pL,       b0 + 16384 + (2 * w + 0) * 1024);
    gll16(pL  + 32, b0 + 16384 + (2 * w + 1) * 1024);
    gll16(pB0,      b0 + 32768 + (4 * w + 0) * 1024);
    gll16(pB0 + 32, b0 + 32768 + (4 * w + 1) * 1024);
    gll16(pB2,      b0 + 32768 + (4 * w + 2) * 1024);
    gll16(pB2 + 32, b0 + 32768 + (4 * w + 3) * 1024);
  }
  asm volatile("s_waitcnt vmcnt(0)" ::: "memory");
  __builtin_amdgcn_s_barrier();

  int cur = 0;
  for (int t = 0; t < NT; ++t) {
    const char* rb = lds + cur * BUF;
    char* nb = lds + (cur ^ 1) * BUF;
    const int koff = (t + 1) * BK;      // next tile's k element offset
    const bool pf = (t + 1 < NT);
#pragma unroll
    for (int kh = 0; kh < 2; ++kh) {
      bf16x8 bq0, bq1, bq2, bq3;
#pragma unroll
      for (int i = 0; i < 4; ++i) {
        const int p = kh * 4 + i;
        if (i == 0) {  // load this k-half's 4 B fragments, register-reused over 4 phases
          bq0 = *reinterpret_cast<const bf16x8*>(rb + 32768 + ((wc * 4 + 0) * 2 + kh) * 1024 + lane * 16);
          bq1 = *reinterpret_cast<const bf16x8*>(rb + 32768 + ((wc * 4 + 1) * 2 + kh) * 1024 + lane * 16);
          bq2 = *reinterpret_cast<const bf16x8*>(rb + 32768 + ((wc * 4 + 2) * 2 + kh) * 1024 + lane * 16);
          bq3 = *reinterpret_cast<const bf16x8*>(rb + 32768 + ((wc * 4 + 3) * 2 + kh) * 1024 + lane * 16);
        }
        const bf16x8 ah = *reinterpret_cast<const bf16x8*>(rb +         ((wr * 4 + i) * 2 + kh) * 1024 + lane * 16);
        const bf16x8 al = *reinterpret_cast<const bf16x8*>(rb + 16384 + ((wr * 4 + i) * 2 + kh) * 1024 + lane * 16);
        if (pf) {  // prefetch tile t+1: 2 gll16 in each of phases 0-3
          if (p == 0) { gll16(pA  + koff, nb + (2 * w + 0) * 1024);
                        gll16(pA  + koff + 32, nb + (2 * w + 1) * 1024); }
          if (p == 1) { gll16(pL  + koff, nb + 16384 + (2 * w + 0) * 1024);
                        gll16(pL  + koff + 32, nb + 16384 + (2 * w + 1) * 1024); }
          if (p == 2) { gll16(pB0 + koff, nb + 32768 + (4 * w + 0) * 1024);
                        gll16(pB0 + koff + 32, nb + 32768 + (4 * w + 1) * 1024); }
          if (p == 3) { gll16(pB2 + koff, nb + 32768 + (4 * w + 2) * 1024);
                        gll16(pB2 + koff + 32, nb + 32768 + (4 * w + 3) * 1024); }
        }
        __builtin_amdgcn_s_barrier();
        asm volatile("s_waitcnt lgkmcnt(0)" ::: "memory");
        __builtin_amdgcn_s_setprio(1);
        acc[i][0] = MFMA(ah, bq0, acc[i][0]);
        acc[i][1] = MFMA(ah, bq1, acc[i][1]);
        acc[i][2] = MFMA(ah, bq2, acc[i][2]);
        acc[i][3] = MFMA(ah, bq3, acc[i][3]);
        acc[i][0] = MFMA(al, bq0, acc[i][0]);
        acc[i][1] = MFMA(al, bq1, acc[i][1]);
        acc[i][2] = MFMA(al, bq2, acc[i][2]);
        acc[i][3] = MFMA(al, bq3, acc[i][3]);
        __builtin_amdgcn_s_setprio(0);
        if (p == 7) asm volatile("s_waitcnt vmcnt(0)" ::: "memory");  // T4: once per tile
        __builtin_amdgcn_s_barrier();
      }
    }
    cur ^= 1;
  }

  // epilogue: out = scales[n]*acc + bias[n]; C/D layout: col=lane&15, row=(lane>>4)*4+reg
#pragma unroll
  for (int j = 0; j < 4; ++j) {
    const int col = col0 + wc * 64 + j * 16 + r16;
    const float s = scales[col];
    const float b = bias[col];
#pragma unroll
    for (int i = 0; i < 4; ++i) {
      const int row = row0 + wr * 64 + i * 16 + kc * 4;
#pragma unroll
      for (int r = 0; r < 4; ++r) {
        out[(size_t)(row + r) * N_DIM + col] = s * acc[i][j][r] + b;
      }
    }
  }
}

extern "C" void kernel_launch(void* const* d_in, const int* in_sizes, int n_in,
                              void* d_out, int out_size, void* d_ws, size_t ws_size,
                              hipStream_t stream) {
  const float* x       = (const float*)d_in[0];
  const int*   qweight = (const int*)d_in[1];
  const int*   qzeros  = (const int*)d_in[2];
  const float* scales  = (const float*)d_in[3];
  // d_in[4] = g_idx: all zeros (single group) -> folded into Bt, unused
  const float* bias    = (const float*)d_in[5];
  float* out = (float*)d_out;

  char* ws = (char*)d_ws;
  unsigned short* bt  = (unsigned short*)ws;                               // 32 MB
  unsigned short* xhi = (unsigned short*)(ws + (size_t)32 * 1024 * 1024);  // 64 MB
  unsigned short* xlo = (unsigned short*)(ws + (size_t)96 * 1024 * 1024);  // 64 MB

  unpack_bt<<<dim3(K_DIM / 64, N_DIM / 32), 256, 0, stream>>>(qweight, qzeros, bt);
  split_x<<<dim3(4096), 256, 0, stream>>>(x, xhi, xlo, T_DIM * K_DIM / 8);
  gemm_dual8<<<dim3((T_DIM / BM) * (N_DIM / BN)), 512, 0, stream>>>(xhi, xlo, bt, scales, bias, out);
}